// Round 8
// baseline (469.977 us; speedup 1.0000x reference)
//
#include <hip/hip_runtime.h>
#include <cstddef>

#define T_SEQ 11
#define STEPS 80

typedef _Float16 f16;
typedef _Float16 f16x4 __attribute__((ext_vector_type(4)));
typedef _Float16 f16x8 __attribute__((ext_vector_type(8)));
typedef float    f32x4 __attribute__((ext_vector_type(4)));

// Gate prescale folded into weights/biases: sigmoid args x -log2(e), tanh
// (n-path) args x +2*log2(e) -> epilogue uses raw exp2/rcp, no per-gate muls.
#define SRC (-1.44269504f)
#define SNC ( 2.88539008f)

__device__ __forceinline__ f32x4 mfma16(f16x8 a, f16x8 b, f32x4 c) {
    return __builtin_amdgcn_mfma_f32_16x16x32_f16(a, b, c, 0, 0, 0);
}
__device__ __forceinline__ float exp2r(float x) { return __builtin_amdgcn_exp2f(x); }

// A-frag: lane holds sc*W[row][k0..k0+7].
__device__ __forceinline__ f16x8 wfrag(const float* __restrict__ W, int row, int k0, float sc) {
    f16x8 r;
    #pragma unroll
    for (int i = 0; i < 8; ++i) r[i] = (f16)(sc * W[row * 64 + k0 + i]);
    return r;
}
// Composed decoder-l0 gi weights: sc*(Wih0[g][0]*fcW[0][k] + Wih0[g][1]*fcW[1][k])
__device__ __forceinline__ f16x8 cfrag(const float* __restrict__ Wih0,
                                       const float* __restrict__ fcW, int row, int k0, float sc) {
    f16x8 r;
    #pragma unroll
    for (int i = 0; i < 8; ++i)
        r[i] = (f16)(sc * (Wih0[row * 2] * fcW[k0 + i] + Wih0[row * 2 + 1] * fcW[64 + k0 + i]));
    return r;
}

// ONE layer's weights per wave (48 regs) — r0-r7 ledger: holding both layers
// (96 regs weights -> ~180 total) pins occupancy at 2 waves/SIMD. Layer-split
// halves the held state so 2 blocks x (1 L0-wave + 1 L1-wave) = 4
// independent streams fit per SIMD at the 128-reg cap.
struct WSet {
    f16x8 xR[2], xZ[2], xN[2];   // gi-source weights (MFMA path)
    f16x8 hR[2], hZ[2], hN[2];   // recurrent weights
};

__device__ __forceinline__ void load_h_frags(WSet& W, const float* __restrict__ Whh,
                                             int jA, int quad)
{
    #pragma unroll
    for (int ks = 0; ks < 2; ++ks) {
        const int k0 = ks * 32 + quad * 8;
        W.hR[ks] = wfrag(Whh, jA,       k0, SRC);
        W.hZ[ks] = wfrag(Whh, jA + 64,  k0, SRC);
        W.hN[ks] = wfrag(Whh, jA + 128, k0, SNC);
    }
}
__device__ __forceinline__ void load_x_frags(WSet& W, const float* __restrict__ Wx,
                                             int jA, int quad)
{
    #pragma unroll
    for (int ks = 0; ks < 2; ++ks) {
        const int k0 = ks * 32 + quad * 8;
        W.xR[ks] = wfrag(Wx, jA,       k0, SRC);
        W.xZ[ks] = wfrag(Wx, jA + 64,  k0, SRC);
        W.xN[ks] = wfrag(Wx, jA + 128, k0, SNC);
    }
}

// One GRU cell on ONE 16-row batch half. Math bit-identical to the r7 cell
// (mt loop removed). Biases from LDS slot CT.
template<bool XM, int CT>
__device__ __forceinline__ void cellH(const WSet& W, const float* __restrict__ sb,
    const f16* __restrict__ Xs, const f16* __restrict__ Hs, f16* __restrict__ Dst,
    f16x4& ho, const f32x4* __restrict__ xw, float2 xv,
    int j4, int ro0, int ro1, int wo)
{
    const f32x4 bR  = *(const f32x4*)(sb + CT * 256 +       j4);
    const f32x4 bZ  = *(const f32x4*)(sb + CT * 256 +  64 + j4);
    const f32x4 bNi = *(const f32x4*)(sb + CT * 256 + 128 + j4);
    const f32x4 bNh = *(const f32x4*)(sb + CT * 256 + 192 + j4);
    f16x8 hb0 = *(const f16x8*)(Hs + ro0);
    f16x8 hb1 = *(const f16x8*)(Hs + ro1);
    f32x4 aR  = mfma16(W.hR[0], hb0, bR);
    f32x4 aZ  = mfma16(W.hZ[0], hb0, bZ);
    f32x4 aNh = mfma16(W.hN[0], hb0, bNh);
    aR  = mfma16(W.hR[1], hb1, aR);
    aZ  = mfma16(W.hZ[1], hb1, aZ);
    aNh = mfma16(W.hN[1], hb1, aNh);
    f32x4 aNi;
    if constexpr (XM) {
        f16x8 xb0 = *(const f16x8*)(Xs + ro0);
        f16x8 xb1 = *(const f16x8*)(Xs + ro1);
        aR  = mfma16(W.xR[0], xb0, aR);    aR  = mfma16(W.xR[1], xb1, aR);
        aZ  = mfma16(W.xZ[0], xb0, aZ);    aZ  = mfma16(W.xZ[1], xb1, aZ);
        aNi = mfma16(W.xN[0], xb0, bNi);   aNi = mfma16(W.xN[1], xb1, aNi);
    } else {
        aR  += xv.x * xw[0] + xv.y * xw[1];
        aZ  += xv.x * xw[2] + xv.y * xw[3];
        aNi  = bNi + xv.x * xw[4] + xv.y * xw[5];
    }
    f16x4 o;
    #pragma unroll
    for (int i = 0; i < 4; ++i) {
        const float r = __builtin_amdgcn_rcpf(1.f + exp2r(aR[i]));
        const float z = __builtin_amdgcn_rcpf(1.f + exp2r(aZ[i]));
        const float n = 1.f - 2.f * __builtin_amdgcn_rcpf(1.f + exp2r(aNi[i] + r * aNh[i]));
        const float h = n + z * ((float)ho[i] - n);
        o[i] = (f16)h;
    }
    ho = o;
    *(f16x4*)(Dst + wo) = o;
}

// 512 threads = 8 waves: wv 0-3 = layer-0 (j-group wv), wv 4-7 = layer-1.
// Batch halves A/B pipelined: tick even = L0(s,A) || L1(s-1,B) || FC(s-1,A);
// tick odd = L0(s,B) || L1(s,A) || FC(s-1,B). One barrier per tick.
// launch_bounds(512,4): 128-reg cap > ~110 natural (one 48-reg WSet held).
__global__ __launch_bounds__(512, 4)
void gru_traj_pipe1(
    const float* __restrict__ x,
    const float* __restrict__ eWih0, const float* __restrict__ eWhh0,
    const float* __restrict__ ebih0, const float* __restrict__ ebhh0,
    const float* __restrict__ eWih1, const float* __restrict__ eWhh1,
    const float* __restrict__ ebih1, const float* __restrict__ ebhh1,
    const float* __restrict__ dWih0, const float* __restrict__ dWhh0,
    const float* __restrict__ dbih0, const float* __restrict__ dbhh0,
    const float* __restrict__ dWih1, const float* __restrict__ dWhh1,
    const float* __restrict__ dbih1, const float* __restrict__ dbhh1,
    const float* __restrict__ fcW,  const float* __restrict__ fcb,
    float* __restrict__ out)
{
    __shared__ f16 h0b[4][1024];        // [parity*2 + half], swizzled, 8 KB
    __shared__ f16 h1b[4][1024];        // 8 KB
    __shared__ float2 xe[T_SEQ * 32];   // [t][row], 2.75 KB
    __shared__ float sbias[4 * 256];    // 4 cell types x {bR,bZ,bNi,bNh}[64]
    __shared__ f16 sfc[1024];           // fc A-frags (2 x 512)
    __shared__ float sfcb[2];

    const int tid  = threadIdx.x;
    const int lane = tid & 63;
    const int wv   = __builtin_amdgcn_readfirstlane(tid >> 6);
    const bool isL0 = wv < 4;
    const int jg   = wv & 3;
    const int quad = lane >> 4;
    const int col  = lane & 15;
    const int r0   = blockIdx.x * 32;

    // ---------------- prologue staging ----------------
    {
        const float2* x2 = (const float2*)x;
        for (int i = tid; i < 32 * T_SEQ; i += 512) {
            const int row = i / T_SEQ, t = i - row * T_SEQ;
            xe[t * 32 + row] = x2[(size_t)r0 * T_SEQ + i];
        }
    }
    for (int i = tid; i < 2048; i += 512) {   // zero parity-0 buffers
        ((f16*)h0b)[i] = (f16)0.f; ((f16*)h1b)[i] = (f16)0.f;
    }
    if (tid < 64) {   // encoder biases (slots 0: enc-l0, 1: enc-l1)
        const int j = tid;
        sbias[       j] = SRC * (ebih0[j] + ebhh0[j]);
        sbias[ 64 + j] = SRC * (ebih0[64 + j] + ebhh0[64 + j]);
        sbias[128 + j] = SNC * ebih0[128 + j];
        sbias[192 + j] = SNC * ebhh0[128 + j];
        sbias[256 +       j] = SRC * (ebih1[j] + ebhh1[j]);
        sbias[256 +  64 + j] = SRC * (ebih1[64 + j] + ebhh1[64 + j]);
        sbias[256 + 128 + j] = SNC * ebih1[128 + j];
        sbias[256 + 192 + j] = SNC * ebhh1[128 + j];
    }
    for (int e = tid; e < 1024; e += 512) {   // fc frag staging (r4-verified layout)
        const int ks = e >> 9, rr = e & 511;
        const int lne = rr >> 3, ki = rr & 7;
        const int c = lne & 15, q = lne >> 4;
        const int k = ks * 32 + q * 8 + ki;
        sfc[ks * 512 + lne * 8 + ki] = (c < 2) ? (f16)fcW[c * 64 + k] : (f16)0.f;
    }
    if (tid < 2) sfcb[tid] = fcb[tid];

    // Swizzle (identical to r7): phys(row,k) = row*64 + (((k>>3)^(row&7))<<3)+(k&7)
    const int c7  = col & 7;
    const int ro0 = col * 64 + ((quad ^ c7) << 3);
    const int ro1 = col * 64 + (((4 + quad) ^ c7) << 3);
    const int wo  = col * 64 + ((((jg << 1) | (quad >> 1)) ^ c7) << 3) + ((quad & 1) << 2);
    const int jA  = jg * 16 + col;
    const int j4  = jg * 16 + quad * 4;

    f16x4 hoA, hoB;
    #pragma unroll
    for (int i = 0; i < 4; ++i) { hoA[i] = (f16)0.f; hoB[i] = (f16)0.f; }

    WSet W;
    f32x4 xw[6];
    if (isL0) {
        load_h_frags(W, eWhh0, jA, quad);
        #pragma unroll
        for (int rg = 0; rg < 4; ++rg) {
            xw[0][rg] = SRC * eWih0[(j4 + rg) * 2];        xw[1][rg] = SRC * eWih0[(j4 + rg) * 2 + 1];
            xw[2][rg] = SRC * eWih0[(64 + j4 + rg) * 2];   xw[3][rg] = SRC * eWih0[(64 + j4 + rg) * 2 + 1];
            xw[4][rg] = SNC * eWih0[(128 + j4 + rg) * 2];  xw[5][rg] = SNC * eWih0[(128 + j4 + rg) * 2 + 1];
        }
    } else {
        load_h_frags(W, eWhh1, jA, quad);
        load_x_frags(W, eWih1, jA, quad);
    }
    __syncthreads();

    // ---------------- encoder: L0enc(t) rd h0[t&1] wr h0[~t&1];
    // L1enc(t) x=h0[~t&1], rd h1[t&1] wr h1[~t&1] ----------------
    #pragma unroll 1
    for (int t = 0; t < T_SEQ; ++t) {
        const int pr = t & 1, pw = pr ^ 1;
        if (isL0) {        // L0enc(t,A)
            const float2 xv = xe[t * 32 + col];
            cellH<false, 0>(W, sbias, nullptr, h0b[pr * 2 + 0], h0b[pw * 2 + 0], hoA, xw, xv, j4, ro0, ro1, wo);
        } else if (t > 0) { // L1enc(t-1,B)
            cellH<true, 1>(W, sbias, h0b[pr * 2 + 1], h1b[pw * 2 + 1], h1b[pr * 2 + 1], hoB, xw, make_float2(0.f, 0.f), j4, ro0, ro1, wo);
        }
        __syncthreads();
        if (isL0) {        // L0enc(t,B)
            const float2 xv = xe[t * 32 + 16 + col];
            cellH<false, 0>(W, sbias, nullptr, h0b[pr * 2 + 1], h0b[pw * 2 + 1], hoB, xw, xv, j4, ro0, ro1, wo);
        } else {           // L1enc(t,A)
            cellH<true, 1>(W, sbias, h0b[pw * 2 + 0], h1b[pr * 2 + 0], h1b[pw * 2 + 0], hoA, xw, make_float2(0.f, 0.f), j4, ro0, ro1, wo);
        }
        __syncthreads();
    }
    if (!isL0)   // drain: L1enc(10,B): x=h0[1][B], rd h1[0][B] wr h1[1][B]
        cellH<true, 1>(W, sbias, h0b[1 * 2 + 1], h1b[0 * 2 + 1], h1b[1 * 2 + 1], hoB, xw, make_float2(0.f, 0.f), j4, ro0, ro1, wo);
    __syncthreads();
    // final: h0 in parity 1, h1 in parity 1 (both halves)

    // ---------------- phase switch ----------------
    if (isL0) {
        load_h_frags(W, dWhh0, jA, quad);
        #pragma unroll
        for (int ks = 0; ks < 2; ++ks) {
            const int k0 = ks * 32 + quad * 8;
            W.xR[ks] = cfrag(dWih0, fcW, jA,       k0, SRC);
            W.xZ[ks] = cfrag(dWih0, fcW, jA + 64,  k0, SRC);
            W.xN[ks] = cfrag(dWih0, fcW, jA + 128, k0, SNC);
        }
        #pragma unroll
        for (int rg = 0; rg < 4; ++rg) {   // dec scalar-x weights (peel only)
            xw[0][rg] = SRC * dWih0[(j4 + rg) * 2];        xw[1][rg] = SRC * dWih0[(j4 + rg) * 2 + 1];
            xw[2][rg] = SRC * dWih0[(64 + j4 + rg) * 2];   xw[3][rg] = SRC * dWih0[(64 + j4 + rg) * 2 + 1];
            xw[4][rg] = SNC * dWih0[(128 + j4 + rg) * 2];  xw[5][rg] = SNC * dWih0[(128 + j4 + rg) * 2 + 1];
        }
    } else {
        load_h_frags(W, dWhh1, jA, quad);
        load_x_frags(W, dWih1, jA, quad);
    }
    if (tid < 64) {   // decoder biases (slots 2: dec-l0 +fc fold, 3: dec-l1)
        const int j = tid;
        const float f0 = fcb[0], f1 = fcb[1];
        sbias[512 +       j] = SRC * (dbih0[j] + dbhh0[j] + dWih0[j * 2] * f0 + dWih0[j * 2 + 1] * f1);
        sbias[512 +  64 + j] = SRC * (dbih0[64 + j] + dbhh0[64 + j] + dWih0[(64 + j) * 2] * f0 + dWih0[(64 + j) * 2 + 1] * f1);
        sbias[512 + 128 + j] = SNC * (dbih0[128 + j] + dWih0[(128 + j) * 2] * f0 + dWih0[(128 + j) * 2 + 1] * f1);
        sbias[512 + 192 + j] = SNC * dbhh0[128 + j];
        sbias[768 +       j] = SRC * (dbih1[j] + dbhh1[j]);
        sbias[768 +  64 + j] = SRC * (dbih1[64 + j] + dbhh1[64 + j]);
        sbias[768 + 128 + j] = SNC * dbih1[128 + j];
        sbias[768 + 192 + j] = SNC * dbhh1[128 + j];
    }
    __syncthreads();

    // FC: L1-wave jg0 owns half A's output rows, jg1 half B's.
    float* op = out + (size_t)(r0 + jg * 16 + col) * (STEPS * 2);
    auto FCOUT = [&](const f16* __restrict__ h1c) {
        f32x4 pb;
        pb[0] = (quad == 0) ? sfcb[0] : 0.f;
        pb[1] = (quad == 0) ? sfcb[1] : 0.f;
        pb[2] = 0.f; pb[3] = 0.f;
        f16x8 fc0 = *(const f16x8*)(sfc + lane * 8);
        f16x8 fc1 = *(const f16x8*)(sfc + 512 + lane * 8);
        f16x8 hb0 = *(const f16x8*)(h1c + ro0);
        f16x8 hb1 = *(const f16x8*)(h1c + ro1);
        f32x4 p = mfma16(fc0, hb0, pb);
        p = mfma16(fc1, hb1, p);
        if (quad == 0) *(float2*)op = make_float2(p[0], p[1]);
        op += 2;
    };

    // ---------------- decoder s=0 peeled (scalar-x, CT=2 as r7) ----------------
    if (isL0) {   // L0dec(0,A): rd h0[1][A] wr h0[0][A]
        const float2 xv = xe[10 * 32 + col];
        cellH<false, 2>(W, sbias, nullptr, h0b[1 * 2 + 0], h0b[0 * 2 + 0], hoA, xw, xv, j4, ro0, ro1, wo);
    }
    __syncthreads();
    if (isL0) {   // L0dec(0,B)
        const float2 xv = xe[10 * 32 + 16 + col];
        cellH<false, 2>(W, sbias, nullptr, h0b[1 * 2 + 1], h0b[0 * 2 + 1], hoB, xw, xv, j4, ro0, ro1, wo);
    } else {      // L1dec(0,A): x=h0[0][A], rd h1[1][A] wr h1[0][A]
        cellH<true, 3>(W, sbias, h0b[0 * 2 + 0], h1b[1 * 2 + 0], h1b[0 * 2 + 0], hoA, xw, make_float2(0.f, 0.f), j4, ro0, ro1, wo);
    }
    __syncthreads();

    // ---------------- decoder s=1..79: L0dec(s) rd h0[pw]+h1[pw], wr h0[pr];
    // L1dec(s) x=h0[pr], rd h1[pw] wr h1[pr]; FC(s-1) rd h1[pw] ----------------
    #pragma unroll 1
    for (int s = 1; s < STEPS; ++s) {
        const int pr = s & 1, pw = pr ^ 1;
        if (isL0) {   // L0dec(s,A)
            cellH<true, 2>(W, sbias, h1b[pw * 2 + 0], h0b[pw * 2 + 0], h0b[pr * 2 + 0], hoA, xw, make_float2(0.f, 0.f), j4, ro0, ro1, wo);
        } else {      // L1dec(s-1,B) + FC(s-1,A) on jg0
            cellH<true, 3>(W, sbias, h0b[pw * 2 + 1], h1b[pr * 2 + 1], h1b[pw * 2 + 1], hoB, xw, make_float2(0.f, 0.f), j4, ro0, ro1, wo);
            if (jg == 0) FCOUT(h1b[pw * 2 + 0]);
        }
        __syncthreads();
        if (isL0) {   // L0dec(s,B)
            cellH<true, 2>(W, sbias, h1b[pw * 2 + 1], h0b[pw * 2 + 1], h0b[pr * 2 + 1], hoB, xw, make_float2(0.f, 0.f), j4, ro0, ro1, wo);
        } else {      // L1dec(s,A) + FC(s-1,B) on jg1
            cellH<true, 3>(W, sbias, h0b[pr * 2 + 0], h1b[pw * 2 + 0], h1b[pr * 2 + 0], hoA, xw, make_float2(0.f, 0.f), j4, ro0, ro1, wo);
            if (jg == 1) FCOUT(h1b[pw * 2 + 1]);
        }
        __syncthreads();
    }
    // drain: L1dec(79,B) + FC(79,A); then FC(79,B). s=79: pr=1.
    if (!isL0) {
        cellH<true, 3>(W, sbias, h0b[1 * 2 + 1], h1b[0 * 2 + 1], h1b[1 * 2 + 1], hoB, xw, make_float2(0.f, 0.f), j4, ro0, ro1, wo);
        if (jg == 0) FCOUT(h1b[1 * 2 + 0]);
    }
    __syncthreads();
    if (!isL0 && jg == 1) FCOUT(h1b[1 * 2 + 1]);
}

extern "C" void kernel_launch(void* const* d_in, const int* in_sizes, int n_in,
                              void* d_out, int out_size, void* d_ws, size_t ws_size,
                              hipStream_t stream) {
    (void)n_in; (void)out_size; (void)d_ws; (void)ws_size;

    const float* x     = (const float*)d_in[0];
    const float* eWih0 = (const float*)d_in[1];
    const float* eWhh0 = (const float*)d_in[2];
    const float* ebih0 = (const float*)d_in[3];
    const float* ebhh0 = (const float*)d_in[4];
    const float* eWih1 = (const float*)d_in[5];
    const float* eWhh1 = (const float*)d_in[6];
    const float* ebih1 = (const float*)d_in[7];
    const float* ebhh1 = (const float*)d_in[8];
    const float* dWih0 = (const float*)d_in[9];
    const float* dWhh0 = (const float*)d_in[10];
    const float* dbih0 = (const float*)d_in[11];
    const float* dbhh0 = (const float*)d_in[12];
    const float* dWih1 = (const float*)d_in[13];
    const float* dWhh1 = (const float*)d_in[14];
    const float* dbih1 = (const float*)d_in[15];
    const float* dbhh1 = (const float*)d_in[16];
    const float* fcW   = (const float*)d_in[17];
    const float* fcb   = (const float*)d_in[18];
    float* out = (float*)d_out;

    const int b = in_sizes[0] / (T_SEQ * 2);   // 32768
    dim3 grid(b / 32), block(512);
    hipLaunchKernelGGL(gru_traj_pipe1, grid, block, 0, stream,
        x, eWih0, eWhh0, ebih0, ebhh0, eWih1, eWhh1, ebih1, ebhh1,
        dWih0, dWhh0, dbih0, dbhh0, dWih1, dWhh1, dbih1, dbhh1,
        fcW, fcb, out);
}